// Round 1
// baseline (353.449 us; speedup 1.0000x reference)
//
#include <hip/hip_runtime.h>

#define TT 512
#define BB 256
#define DD 2048
#define DQ 2049   // D + Q (Q == 1)

// ---- fast transcendentals (v_exp_f32 / v_rcp_f32) -------------------------
__device__ __forceinline__ float fexp(float x) {
    return exp2f(x * 1.442695040888963f);      // e^x = 2^(x*log2 e)
}
__device__ __forceinline__ float frcp(float x) {
    return __builtin_amdgcn_rcpf(x);
}
__device__ __forceinline__ float ftanh(float x) {
    // tanh(x) = 1 - 2/(1+e^{2x}); saturates correctly for |x| large
    return 1.f - 2.f * frcp(1.f + fexp(2.f * x));
}
__device__ __forceinline__ float fsig(float x) {
    return frcp(1.f + fexp(-x));
}

// ---- Kernel 1: pre[row][g] = dot(x[row,0:2048], lw[g,0:2048]) + lb[g] -----
// One wave per row. Gate weights live in 128 VGPRs, loaded once per wave.
__global__ __launch_bounds__(256) void qlstm_gemm(
    const float* __restrict__ x,    // [T*B, 2048]
    const float* __restrict__ lw,   // [4, 2049]
    const float* __restrict__ lb,   // [4]
    float4* __restrict__ pre_out,   // [T*B]
    int nwaves)
{
    const int lane = threadIdx.x & 63;
    const int wid  = (blockIdx.x << 2) + (threadIdx.x >> 6);

    // w[it][g] covers d = it*256 + lane*4 .. +3  (full 2048 across 8 its)
    // lw rows have stride 2049 floats -> odd-g rows are 16B-misaligned,
    // so load weights scalar (init-only cost).
    float4 w[8][4];
#pragma unroll
    for (int it = 0; it < 8; ++it) {
        const int d = it * 256 + lane * 4;
#pragma unroll
        for (int g = 0; g < 4; ++g) {
            const float* p = lw + g * DQ + d;
            w[it][g] = make_float4(p[0], p[1], p[2], p[3]);
        }
    }
    const float b0 = lb[0], b1 = lb[1], b2 = lb[2], b3 = lb[3];

    for (int row = wid; row < TT * BB; row += nwaves) {
        const float* xr = x + (size_t)row * DD + lane * 4;
        float a0 = 0.f, a1 = 0.f, a2 = 0.f, a3 = 0.f;
#pragma unroll
        for (int it = 0; it < 8; ++it) {
            const float4 xv = *reinterpret_cast<const float4*>(xr + it * 256);
            a0 += xv.x * w[it][0].x + xv.y * w[it][0].y + xv.z * w[it][0].z + xv.w * w[it][0].w;
            a1 += xv.x * w[it][1].x + xv.y * w[it][1].y + xv.z * w[it][1].z + xv.w * w[it][1].w;
            a2 += xv.x * w[it][2].x + xv.y * w[it][2].y + xv.z * w[it][2].z + xv.w * w[it][2].w;
            a3 += xv.x * w[it][3].x + xv.y * w[it][3].y + xv.z * w[it][3].z + xv.w * w[it][3].w;
        }
#pragma unroll
        for (int s = 32; s; s >>= 1) {
            a0 += __shfl_xor(a0, s);
            a1 += __shfl_xor(a1, s);
            a2 += __shfl_xor(a2, s);
            a3 += __shfl_xor(a3, s);
        }
        if (lane == 0)
            pre_out[row] = make_float4(a0 + b0, a1 + b1, a2 + b2, a3 + b3);
    }
}

// ---- Kernel 2: sequential LSTM scan, one thread per batch element ---------
__global__ __launch_bounds__(256) void qlstm_scan(
    const float4* __restrict__ pre,   // [T*B]: x-dot + lb, per gate
    const float* __restrict__ lw,     // [4,2049] -> h-weight at col 2048
    const float* __restrict__ ew,     // enc_w [4]
    const float* __restrict__ ebv,    // enc_b [4]
    const float* __restrict__ rx,     // [4]
    const float* __restrict__ mw,     // meas_w [4]
    const float* __restrict__ mb,     // meas_b [4]
    float* __restrict__ out)          // [T*B + B + B]
{
    const int b = threadIdx.x;

    float whx[4], al[4], be[4], mww[4], mbb[4];
#pragma unroll
    for (int g = 0; g < 4; ++g) {
        whx[g] = lw[g * DQ + DD];      // h column
        al[g]  = rx[g] * ew[g];        // fold encoder*rx
        be[g]  = rx[g] * ebv[g];
        mww[g] = mw[g];
        mbb[g] = mb[g];
    }

    float h = 0.f, c = 0.f;

    // group-of-8 double-buffered prefetch; all indices compile-time constant
    float4 cur[8], nxt[8];
#pragma unroll
    for (int j = 0; j < 8; ++j) cur[j] = pre[j * BB + b];

    for (int t0 = 0; t0 < TT; t0 += 8) {
        const int tn = t0 + 8;
        if (tn < TT) {
#pragma unroll
            for (int j = 0; j < 8; ++j) nxt[j] = pre[(tn + j) * BB + b];
        }
#pragma unroll
        for (int j = 0; j < 8; ++j) {
            const float4 pc = cur[j];
            const float p0 = pc.x + h * whx[0];
            const float p1 = pc.y + h * whx[1];
            const float p2 = pc.z + h * whx[2];
            const float p3 = pc.w + h * whx[3];
            const float s0 = ftanh(al[0] * p0 + be[0]);
            const float s1 = ftanh(al[1] * p1 + be[1]);
            const float s2 = ftanh(al[2] * p2 + be[2]);
            const float s3 = ftanh(al[3] * p3 + be[3]);
            const float v0 = s0 * mww[0] + mbb[0];
            const float v1 = s1 * mww[1] + mbb[1];
            const float v2 = s2 * mww[2] + mbb[2];
            const float v3 = s3 * mww[3] + mbb[3];
            const float f  = fsig(v0);
            const float i  = fsig(v1);
            const float gg = ftanh(v2);
            const float o  = fsig(v3);
            c = f * c + i * gg;
            h = o * ftanh(c);
            out[(t0 + j) * BB + b] = h;
        }
#pragma unroll
        for (int j = 0; j < 8; ++j) cur[j] = nxt[j];
    }

    out[TT * BB + b]      = h;   // final hx
    out[TT * BB + BB + b] = c;   // final cx
}

extern "C" void kernel_launch(void* const* d_in, const int* in_sizes, int n_in,
                              void* d_out, int out_size, void* d_ws, size_t ws_size,
                              hipStream_t stream) {
    const float* x   = (const float*)d_in[0];   // [512,256,2048]
    const float* lw  = (const float*)d_in[1];   // [4,1,2049]
    const float* lb  = (const float*)d_in[2];   // [4,1]
    const float* ew  = (const float*)d_in[3];   // [4,1,1]
    const float* ebv = (const float*)d_in[4];   // [4,1]
    const float* rx  = (const float*)d_in[5];   // [4]
    const float* mw  = (const float*)d_in[6];   // [4,1,1]
    const float* mb  = (const float*)d_in[7];   // [4,1]
    float* out = (float*)d_out;
    float4* pre = (float4*)d_ws;                // needs T*B*16 = 2 MiB

    const int blocks = 2048;                    // 8192 waves, 16 rows each
    qlstm_gemm<<<blocks, 256, 0, stream>>>(x, lw, lb, pre, blocks * 4);
    qlstm_scan<<<1, 256, 0, stream>>>(pre, lw, ew, ebv, rx, mw, mb, out);
}